// Round 7
// baseline (427.190 us; speedup 1.0000x reference)
//
#include <hip/hip_runtime.h>
#include <hip/hip_fp8.h>
#include <math.h>

#define B_SZ 512
#define C_SZ 100000
#define D_SZ 512

#define BM 256
#define BN 128
#define BK 64
#define NTILES 782          // ceil(100000/128)
#define MT 4                // 1024 rows / BM
#define NBLK (NTILES * MT)  // 3128 (divisible by 8)
#define KSTEPS 8            // 512 / 64
#define DEPTH 3

typedef __attribute__((ext_vector_type(4))) float f32x4;
typedef __attribute__((ext_vector_type(16))) float f32x16;
typedef __attribute__((ext_vector_type(4))) int i32x4;
typedef __attribute__((ext_vector_type(8))) int i32x8;

#define UNITY_SCALE 0x7F7F7F7F   // e8m0 127 = 2^0 in all byte slots

__device__ __forceinline__ void gload_lds16(const void* gptr, void* lptr) {
  __builtin_amdgcn_global_load_lds(
      (const __attribute__((address_space(1))) void*)gptr,
      (__attribute__((address_space(3))) void*)lptr,
      16, 0, 0);
}

__device__ __forceinline__ unsigned char f2fp8(float x) {
  __hip_fp8_e4m3 h(x);
  return (unsigned char)h.__x;
}
__device__ __forceinline__ float fp82f(unsigned int u) {
  __hip_fp8_e4m3 h;
  h.__x = (unsigned char)u;
  return (float)h;
}
__device__ __forceinline__ unsigned int pack4f8(float a, float b, float c, float d) {
  return (unsigned int)f2fp8(a) | ((unsigned int)f2fp8(b) << 8) |
         ((unsigned int)f2fp8(c) << 16) | ((unsigned int)f2fp8(d) << 24);
}

// ---------------- kernel 1: normalize weight rows -> fp8 ----------------
__global__ __launch_bounds__(256) void k_norm_w(const float* __restrict__ w,
                                                unsigned char* __restrict__ w8) {
  const int row = blockIdx.x * 4 + (threadIdx.x >> 6);
  const int lane = threadIdx.x & 63;
  const float4* wr = (const float4*)(w + (size_t)row * D_SZ);
  float4 v0 = wr[lane];
  float4 v1 = wr[64 + lane];
  float ss = v0.x*v0.x + v0.y*v0.y + v0.z*v0.z + v0.w*v0.w
           + v1.x*v1.x + v1.y*v1.y + v1.z*v1.z + v1.w*v1.w;
  #pragma unroll
  for (int o = 32; o; o >>= 1) ss += __shfl_xor(ss, o, 64);
  const float rn = __builtin_amdgcn_rsqf(fmaxf(ss, 1e-24f));
  unsigned int* out = (unsigned int*)(w8 + (size_t)row * D_SZ);
  out[lane] = pack4f8(v0.x * rn, v0.y * rn, v0.z * rn, v0.w * rn);
  out[64 + lane] = pack4f8(v1.x * rn, v1.y * rn, v1.z * rn, v1.w * rn);
}

// ------- kernel 2: normalize embeddings, gather w_y, per-row params -------
// A8 layout: row 2b = fp8(e_hat[b]), row 2b+1 = fp8 w_hat[label[b]] (bytes copied)
__global__ __launch_bounds__(64) void k_prep(const float* __restrict__ e,
                                             const int* __restrict__ labels,
                                             const unsigned char* __restrict__ w8,
                                             unsigned char* __restrict__ A8,
                                             float4* __restrict__ params) {
  const int b = blockIdx.x;
  const int lane = threadIdx.x;
  const float4* er = (const float4*)(e + (size_t)b * D_SZ);
  float4 v0 = er[lane], v1 = er[64 + lane];
  float ss = v0.x*v0.x + v0.y*v0.y + v0.z*v0.z + v0.w*v0.w
           + v1.x*v1.x + v1.y*v1.y + v1.z*v1.z + v1.w*v1.w;
  #pragma unroll
  for (int o = 32; o; o >>= 1) ss += __shfl_xor(ss, o, 64);
  const float rn = __builtin_amdgcn_rsqf(fmaxf(ss, 1e-24f));
  v0.x *= rn; v0.y *= rn; v0.z *= rn; v0.w *= rn;
  v1.x *= rn; v1.y *= rn; v1.z *= rn; v1.w *= rn;

  unsigned int* arow_e = (unsigned int*)(A8 + (size_t)(2 * b) * D_SZ);
  arow_e[lane] = pack4f8(v0.x, v0.y, v0.z, v0.w);
  arow_e[64 + lane] = pack4f8(v1.x, v1.y, v1.z, v1.w);

  const int lab = labels[b];
  const unsigned int* wr = (const unsigned int*)(w8 + (size_t)lab * D_SZ);
  unsigned int w0 = wr[lane], w1 = wr[64 + lane];
  unsigned int* arow_w = (unsigned int*)(A8 + (size_t)(2 * b + 1) * D_SZ);
  arow_w[lane] = w0;
  arow_w[64 + lane] = w1;

  float d = v0.x * fp82f(w0 & 255) + v0.y * fp82f((w0 >> 8) & 255)
          + v0.z * fp82f((w0 >> 16) & 255) + v0.w * fp82f(w0 >> 24)
          + v1.x * fp82f(w1 & 255) + v1.y * fp82f((w1 >> 8) & 255)
          + v1.z * fp82f((w1 >> 16) & 255) + v1.w * fp82f(w1 >> 24);
  #pragma unroll
  for (int o = 32; o; o >>= 1) d += __shfl_xor(d, o, 64);

  if (lane == 0) {
    const float cos_m = 0.877582561890372716f;  // cos(0.5)
    const float sin_m = 0.479425538604203000f;  // sin(0.5)
    float cos_t = fminf(fmaxf(d, -1.0f), 1.0f);
    float sin_t = sqrtf(fmaxf(1.0f - cos_t * cos_t, 0.0f));
    float cos_tm = cos_t * cos_m - sin_t * sin_m;
    float sin_tm = sin_t * cos_m + cos_t * sin_m;
    float inv_st = 1.0f / fmaxf(sin_t, 1e-20f);
    params[b] = make_float4(cos_tm, sin_m * inv_st, sin_tm * inv_st, 0.0f);
  }
}

// -- kernel 3: MX fp8 32x32x64 GEMM (unity scales), depth-3 pipeline --------
__device__ __forceinline__ float termf(float de, float dwy, float4 p, bool kill) {
  float c = fminf(fmaxf(de, -1.0f), 1.0f);
  float s = p.z * dwy - p.y * de;            // (sin_tm*dwy - sin_m*de)/sin_t
  float x = fmaxf(fmaf(-2.0f, s, 2.0f), 1e-20f);
  float t = (c - p.x) * __builtin_amdgcn_rsqf(x);
  float r = __expf(t);
  return kill ? 0.0f : r;
}

__global__ __launch_bounds__(512, 4) void k_gemm(const unsigned char* __restrict__ A8,
                                                 const unsigned char* __restrict__ W8,
                                                 const float4* __restrict__ params,
                                                 const int* __restrict__ labels,
                                                 float* __restrict__ part) {
  // Fragment-ordered fp8 LDS for 32x32x64 operands.
  // Frag f (2 KB) holds rows [f*32, f*32+32) of the tile; within a frag the
  // two 16B k-chunks of lane l sit at f*2048 + l*16 and f*2048 + 1024 + l*16
  // (k-halves split so every ds_read_b128 is lane-contiguous, stride 16).
  __shared__ __align__(32) unsigned char At[DEPTH][BM * BK];   // 3 x 16 KB
  __shared__ __align__(32) unsigned char Bt[DEPTH][BN * BK];   // 3 x 8 KB
  __shared__ float ered[128];
  __shared__ float4 pl[128];
  __shared__ int ll[128];

  const int bid = blockIdx.x;
  const int p = (bid & 7) * (NBLK / 8) + (bid >> 3);  // XCD-chunked remap
  const int nt = p >> 2, mt = p & 3;                  // mt fastest within XCD
  const int t = threadIdx.x;
  const int w = t >> 6, l = t & 63;
  const int m0 = mt * BM;
  const int n0 = nt * BN;
  const int b0 = mt * (BM / 2);

  if (t < 128) {
    ered[t] = 0.0f;
    pl[t] = params[b0 + t];
    ll[t] = labels[b0 + t];
  }

  // Staging source offsets (fp8 bytes). Thread t stages 16B slots:
  // A slots {t, 512+t}, B slot {t}; LDS dest = slot*16 (linear, wave-uniform
  // base + lane*16).  slot s -> row (s>>7)*32 + (s&31),
  //                          k = ((s>>5)&1)*32 + ((s>>6)&1)*16.
  const int kpart = ((t >> 5) & 1) * 32 + ((t >> 6) & 1) * 16;
  const int aoffs0 = (m0 + (t >> 7) * 32 + (t & 31)) * D_SZ + kpart;
  const int aoffs1 = aoffs0 + 128 * D_SZ;
  int brow_s = n0 + (t >> 7) * 32 + (t & 31);
  if (brow_s >= C_SZ) brow_s = C_SZ - 1;   // clamp; masked in epilogue
  const int boffs = brow_s * D_SZ + kpart;

  f32x16 acc[2][2] = {};
  const int wn_ = (w & 1) * 64;        // wave n-origin (of 128)
  const int fA = (w >> 1) * 2;         // A frag base (0..7), wave owns 64 rows
  const int fB = (w & 1) * 2;          // B frag base (0..3)
  const int hi = l >> 5;

#define STAGE(d, ts)                                                        \
  do {                                                                      \
    const int k0_ = (ts) * BK;                                              \
    gload_lds16(A8 + aoffs0 + k0_, (void*)(At[d] + t * 16));                \
    gload_lds16(A8 + aoffs1 + k0_, (void*)(At[d] + (512 + t) * 16));        \
    gload_lds16(W8 + (size_t)(boffs + k0_), (void*)(Bt[d] + t * 16));       \
  } while (0)

  // ---- prologue: stage tiles 0,1,2 ----
  STAGE(0, 0);
  STAGE(1, 1);
  STAGE(2, 2);
  asm volatile("s_waitcnt vmcnt(6) lgkmcnt(0)" ::: "memory");  // tile 0 landed
  __builtin_amdgcn_s_barrier();

  // ---- main loop: one barrier per step, vmcnt never drained to 0 ----
  #pragma unroll
  for (int step = 0; step < KSTEPS; ++step) {
    const int d = step % DEPTH;
    i32x8 av[2], bv[2];
    #pragma unroll
    for (int mf = 0; mf < 2; ++mf) {
      i32x4 lo = *(const i32x4*)(At[d] + (fA + mf) * 2048 + l * 16);
      i32x4 hig = *(const i32x4*)(At[d] + (fA + mf) * 2048 + 1024 + l * 16);
      av[mf] = __builtin_shufflevector(lo, hig, 0, 1, 2, 3, 4, 5, 6, 7);
    }
    #pragma unroll
    for (int nf = 0; nf < 2; ++nf) {
      i32x4 lo = *(const i32x4*)(Bt[d] + (fB + nf) * 2048 + l * 16);
      i32x4 hig = *(const i32x4*)(Bt[d] + (fB + nf) * 2048 + 1024 + l * 16);
      bv[nf] = __builtin_shufflevector(lo, hig, 0, 1, 2, 3, 4, 5, 6, 7);
    }
    __builtin_amdgcn_s_setprio(1);
    #pragma unroll
    for (int mf = 0; mf < 2; ++mf)
      #pragma unroll
      for (int nf = 0; nf < 2; ++nf)
        acc[mf][nf] = __builtin_amdgcn_mfma_scale_f32_32x32x64_f8f6f4(
            av[mf], bv[nf], acc[mf][nf], 0, 0,   // cbsz=fp8, blgp=fp8
            0, UNITY_SCALE, 0, UNITY_SCALE);
    __builtin_amdgcn_s_setprio(0);
    if (step < KSTEPS - 1) {
      // newest 3 vmem = last iteration's stage; tile step+1 landed
      asm volatile("s_waitcnt vmcnt(3)" ::: "memory");
      __builtin_amdgcn_s_barrier();
      if (step + DEPTH < KSTEPS)
        STAGE(d, step + DEPTH);
    }
  }
#undef STAGE

  // Epilogue. 32x32 C/D layout: col = lane&31, row = (r&3)+8*(r>>2)+4*hi.
  // Interleaved A rows: even row 2b = dot_e, odd = dot_wy -> regs (r, r+1).
  #pragma unroll
  for (int mf = 0; mf < 2; ++mf) {
    #pragma unroll
    for (int rp = 0; rp < 8; ++rp) {
      const int r = 2 * rp;
      const int lb = (w >> 1) * 32 + mf * 16 + (rp & 1) + 4 * (rp >> 1) + 2 * hi;
      float4 pp = pl[lb];
      int lab = ll[lb];
      float s = 0.0f;
      #pragma unroll
      for (int nf = 0; nf < 2; ++nf) {
        int j = n0 + wn_ + nf * 32 + (l & 31);
        bool kill = (j >= C_SZ) || (j == lab);
        s += termf(acc[mf][nf][r], acc[mf][nf][r + 1], pp, kill);
      }
      #pragma unroll
      for (int o = 1; o < 32; o <<= 1) s += __shfl_xor(s, o, 64);
      if ((l & 31) == 0) atomicAdd(&ered[lb], s);
    }
  }
  __syncthreads();
  if (t < 128) part[(size_t)(b0 + t) * NTILES + nt] = ered[t];
}

// ---------------- kernel 4a: per-batch row sum + log1p ----------------
__global__ __launch_bounds__(256) void k_rowsum(const float* __restrict__ part,
                                                float* __restrict__ rowsum) {
  const int b = blockIdx.x;
  float s = 0.0f;
  for (int i = threadIdx.x; i < NTILES; i += 256) s += part[(size_t)b * NTILES + i];
  #pragma unroll
  for (int o = 32; o; o >>= 1) s += __shfl_xor(s, o, 64);
  __shared__ float red[4];
  if ((threadIdx.x & 63) == 0) red[threadIdx.x >> 6] = s;
  __syncthreads();
  if (threadIdx.x == 0)
    rowsum[b] = log1pf(red[0] + red[1] + red[2] + red[3]);
}

// ---------------- kernel 4b: final mean ----------------
__global__ __launch_bounds__(512) void k_final(const float* __restrict__ rowsum,
                                               float* __restrict__ out) {
  const int b = threadIdx.x;
  float v = rowsum[b];
  __shared__ float red[512];
  red[b] = v;
  __syncthreads();
  #pragma unroll
  for (int o = 256; o; o >>= 1) {
    if (b < o) red[b] += red[b + o];
    __syncthreads();
  }
  if (b == 0) out[0] = red[0] / (float)B_SZ;
}

extern "C" void kernel_launch(void* const* d_in, const int* in_sizes, int n_in,
                              void* d_out, int out_size, void* d_ws, size_t ws_size,
                              hipStream_t stream) {
  const float* emb = (const float*)d_in[0];
  const int* labels = (const int*)d_in[1];
  const float* w = (const float*)d_in[2];

  char* ws = (char*)d_ws;
  unsigned char* w8 = (unsigned char*)ws;                  // 100000*512 B
  size_t off = (size_t)C_SZ * D_SZ;
  unsigned char* A8 = (unsigned char*)(ws + off);          // 1024*512 B
  off += (size_t)2 * B_SZ * D_SZ;
  float4* params = (float4*)(ws + off);                    // 512*16 B
  off += (size_t)B_SZ * 16;
  float* part = (float*)(ws + off);                        // 512*782*4 B
  off += (size_t)B_SZ * NTILES * 4;
  float* rowsum = (float*)(ws + off);                      // 512*4 B
  off += (size_t)B_SZ * 4;

  k_norm_w<<<dim3(C_SZ / 4), dim3(256), 0, stream>>>(w, w8);
  k_prep<<<dim3(B_SZ), dim3(64), 0, stream>>>(emb, labels, w8, A8, params);
  k_gemm<<<dim3(NBLK), dim3(512), 0, stream>>>(A8, w8, params, labels, part);
  k_rowsum<<<dim3(B_SZ), dim3(256), 0, stream>>>(part, rowsum);
  k_final<<<dim3(1), dim3(512), 0, stream>>>(rowsum, (float*)d_out);
}

// Round 8
// 146.224 us; speedup vs baseline: 2.9215x; 2.9215x over previous
//
#include <hip/hip_runtime.h>
#include <hip/hip_fp8.h>
#include <math.h>

#define B_SZ 512
#define C_SZ 100000
#define D_SZ 512

#define BM 128
#define BN 128
#define BK 64
#define NTILES 782          // ceil(100000/128)
#define MT 8                // 1024 rows / BM
#define NBLK (NTILES * MT)  // 6256 (divisible by 8)
#define KSTEPS 8            // 512 / 64
#define DEPTH 3

typedef __attribute__((ext_vector_type(4))) float f32x4;
typedef __attribute__((ext_vector_type(16))) float f32x16;
typedef __attribute__((ext_vector_type(4))) int i32x4;
typedef __attribute__((ext_vector_type(8))) int i32x8;

#define UNITY_SCALE 0x7F7F7F7F   // e8m0 127 = 2^0 in all byte slots

__device__ __forceinline__ void gload_lds16(const void* gptr, void* lptr) {
  __builtin_amdgcn_global_load_lds(
      (const __attribute__((address_space(1))) void*)gptr,
      (__attribute__((address_space(3))) void*)lptr,
      16, 0, 0);
}

__device__ __forceinline__ unsigned char f2fp8(float x) {
  __hip_fp8_e4m3 h(x);
  return (unsigned char)h.__x;
}
__device__ __forceinline__ float fp82f(unsigned int u) {
  __hip_fp8_e4m3 h;
  h.__x = (unsigned char)u;
  return (float)h;
}
__device__ __forceinline__ unsigned int pack4f8(float a, float b, float c, float d) {
  return (unsigned int)f2fp8(a) | ((unsigned int)f2fp8(b) << 8) |
         ((unsigned int)f2fp8(c) << 16) | ((unsigned int)f2fp8(d) << 24);
}

// ---------------- kernel 1: normalize weight rows -> fp8 ----------------
__global__ __launch_bounds__(256) void k_norm_w(const float* __restrict__ w,
                                                unsigned char* __restrict__ w8) {
  const int row = blockIdx.x * 4 + (threadIdx.x >> 6);
  const int lane = threadIdx.x & 63;
  const float4* wr = (const float4*)(w + (size_t)row * D_SZ);
  float4 v0 = wr[lane];
  float4 v1 = wr[64 + lane];
  float ss = v0.x*v0.x + v0.y*v0.y + v0.z*v0.z + v0.w*v0.w
           + v1.x*v1.x + v1.y*v1.y + v1.z*v1.z + v1.w*v1.w;
  #pragma unroll
  for (int o = 32; o; o >>= 1) ss += __shfl_xor(ss, o, 64);
  const float rn = __builtin_amdgcn_rsqf(fmaxf(ss, 1e-24f));
  unsigned int* out = (unsigned int*)(w8 + (size_t)row * D_SZ);
  out[lane] = pack4f8(v0.x * rn, v0.y * rn, v0.z * rn, v0.w * rn);
  out[64 + lane] = pack4f8(v1.x * rn, v1.y * rn, v1.z * rn, v1.w * rn);
}

// ------- kernel 2: normalize embeddings, gather w_y, per-row params -------
// A8 layout: row 2b = fp8(e_hat[b]), row 2b+1 = fp8 w_hat[label[b]] (bytes copied)
__global__ __launch_bounds__(64) void k_prep(const float* __restrict__ e,
                                             const int* __restrict__ labels,
                                             const unsigned char* __restrict__ w8,
                                             unsigned char* __restrict__ A8,
                                             float4* __restrict__ params) {
  const int b = blockIdx.x;
  const int lane = threadIdx.x;
  const float4* er = (const float4*)(e + (size_t)b * D_SZ);
  float4 v0 = er[lane], v1 = er[64 + lane];
  float ss = v0.x*v0.x + v0.y*v0.y + v0.z*v0.z + v0.w*v0.w
           + v1.x*v1.x + v1.y*v1.y + v1.z*v1.z + v1.w*v1.w;
  #pragma unroll
  for (int o = 32; o; o >>= 1) ss += __shfl_xor(ss, o, 64);
  const float rn = __builtin_amdgcn_rsqf(fmaxf(ss, 1e-24f));
  v0.x *= rn; v0.y *= rn; v0.z *= rn; v0.w *= rn;
  v1.x *= rn; v1.y *= rn; v1.z *= rn; v1.w *= rn;

  unsigned int* arow_e = (unsigned int*)(A8 + (size_t)(2 * b) * D_SZ);
  arow_e[lane] = pack4f8(v0.x, v0.y, v0.z, v0.w);
  arow_e[64 + lane] = pack4f8(v1.x, v1.y, v1.z, v1.w);

  const int lab = labels[b];
  const unsigned int* wr = (const unsigned int*)(w8 + (size_t)lab * D_SZ);
  unsigned int w0 = wr[lane], w1 = wr[64 + lane];
  unsigned int* arow_w = (unsigned int*)(A8 + (size_t)(2 * b + 1) * D_SZ);
  arow_w[lane] = w0;
  arow_w[64 + lane] = w1;

  float d = v0.x * fp82f(w0 & 255) + v0.y * fp82f((w0 >> 8) & 255)
          + v0.z * fp82f((w0 >> 16) & 255) + v0.w * fp82f(w0 >> 24)
          + v1.x * fp82f(w1 & 255) + v1.y * fp82f((w1 >> 8) & 255)
          + v1.z * fp82f((w1 >> 16) & 255) + v1.w * fp82f(w1 >> 24);
  #pragma unroll
  for (int o = 32; o; o >>= 1) d += __shfl_xor(d, o, 64);

  if (lane == 0) {
    const float cos_m = 0.877582561890372716f;  // cos(0.5)
    const float sin_m = 0.479425538604203000f;  // sin(0.5)
    float cos_t = fminf(fmaxf(d, -1.0f), 1.0f);
    float sin_t = sqrtf(fmaxf(1.0f - cos_t * cos_t, 0.0f));
    float cos_tm = cos_t * cos_m - sin_t * sin_m;
    float sin_tm = sin_t * cos_m + cos_t * sin_m;
    float inv_st = 1.0f / fmaxf(sin_t, 1e-20f);
    params[b] = make_float4(cos_tm, sin_m * inv_st, sin_tm * inv_st, 0.0f);
  }
}

// -- kernel 3: MX fp8 32x32x64 GEMM (unity scales), low-pressure geometry ----
// BM=128 BN=128, 8 waves, 2 tiles/wave -> acc = 2 x f32x16 = 32 VGPR.
__device__ __forceinline__ float termf(float de, float dwy, float4 p, bool kill) {
  float c = fminf(fmaxf(de, -1.0f), 1.0f);
  float s = p.z * dwy - p.y * de;            // (sin_tm*dwy - sin_m*de)/sin_t
  float x = fmaxf(fmaf(-2.0f, s, 2.0f), 1e-20f);
  float t = (c - p.x) * __builtin_amdgcn_rsqf(x);
  float r = __expf(t);
  return kill ? 0.0f : r;
}

__global__ __launch_bounds__(512, 4) void k_gemm(const unsigned char* __restrict__ A8,
                                                 const unsigned char* __restrict__ W8,
                                                 const float4* __restrict__ params,
                                                 const int* __restrict__ labels,
                                                 float* __restrict__ part) {
  // Fragment-ordered fp8 LDS: frag f (32 rows x 64 k = 2 KB) at f*2048.
  // Lane l: lo 16B at f*2048 + l*16, hi 16B at f*2048 + 1024 + l*16.
  // Source-k mapping is identical for A and B (square-MFMA operand symmetry
  // + K-permutation invariance; verified numerically in R6/R7).
  __shared__ __align__(32) unsigned char At[DEPTH][BM * BK];   // 3 x 8 KB
  __shared__ __align__(32) unsigned char Bt[DEPTH][BN * BK];   // 3 x 8 KB
  __shared__ float ered[64];
  __shared__ float4 pl[64];
  __shared__ int ll[64];

  const int bid = blockIdx.x;
  const int p = (bid & 7) * (NBLK / 8) + (bid >> 3);  // XCD-chunked remap
  const int nt = p >> 3, mt = p & 7;                  // mt fastest within XCD
  const int t = threadIdx.x;
  const int w = t >> 6, l = t & 63;
  const int m0 = mt * BM;
  const int n0 = nt * BN;
  const int b0 = mt * 64;

  if (t < 64) {
    ered[t] = 0.0f;
    pl[t] = params[b0 + t];
    ll[t] = labels[b0 + t];
  }

  // Staging: thread t stages A slot t and B slot t (16 B each).
  // slot s: frag = s>>7, row_in_frag = s&31, kpart = ((s>>5)&1)*32 + ((s>>6)&1)*16.
  const int kpart = ((t >> 5) & 1) * 32 + ((t >> 6) & 1) * 16;
  const int aoffs = (m0 + (t >> 7) * 32 + (t & 31)) * D_SZ + kpart;
  int brow_s = n0 + (t >> 7) * 32 + (t & 31);
  if (brow_s >= C_SZ) brow_s = C_SZ - 1;   // clamp; masked in epilogue
  const int boffs = brow_s * D_SZ + kpart;

  f32x16 accA = {}, accB = {};          // the wave's two 32x32 tiles
  const int fA = w & 3;                  // A frag (m-frag) owned by this wave
  const int fB0 = (w >> 2) * 2;          // B frag base (n-frags fB0, fB0+1)
  const int hi = l >> 5;

#define STAGE(d, ts)                                                        \
  do {                                                                      \
    const int k0_ = (ts) * BK;                                              \
    gload_lds16(A8 + aoffs + k0_, (void*)(At[d] + t * 16));                 \
    gload_lds16(W8 + (size_t)(boffs + k0_), (void*)(Bt[d] + t * 16));       \
  } while (0)

  // ---- prologue: stage tiles 0,1,2 ----
  STAGE(0, 0);
  STAGE(1, 1);
  STAGE(2, 2);
  asm volatile("s_waitcnt vmcnt(4) lgkmcnt(0)" ::: "memory");  // tile 0 landed
  __builtin_amdgcn_s_barrier();

  // ---- main loop: one barrier per step, vmcnt never drained to 0 ----
  #pragma unroll
  for (int step = 0; step < KSTEPS; ++step) {
    const int d = step % DEPTH;
    i32x4 alo = *(const i32x4*)(At[d] + fA * 2048 + l * 16);
    i32x4 ahi = *(const i32x4*)(At[d] + fA * 2048 + 1024 + l * 16);
    i32x8 av = __builtin_shufflevector(alo, ahi, 0, 1, 2, 3, 4, 5, 6, 7);
    i32x4 b0lo = *(const i32x4*)(Bt[d] + fB0 * 2048 + l * 16);
    i32x4 b0hi = *(const i32x4*)(Bt[d] + fB0 * 2048 + 1024 + l * 16);
    i32x8 bv0 = __builtin_shufflevector(b0lo, b0hi, 0, 1, 2, 3, 4, 5, 6, 7);
    i32x4 b1lo = *(const i32x4*)(Bt[d] + (fB0 + 1) * 2048 + l * 16);
    i32x4 b1hi = *(const i32x4*)(Bt[d] + (fB0 + 1) * 2048 + 1024 + l * 16);
    i32x8 bv1 = __builtin_shufflevector(b1lo, b1hi, 0, 1, 2, 3, 4, 5, 6, 7);
    __builtin_amdgcn_s_setprio(1);
    accA = __builtin_amdgcn_mfma_scale_f32_32x32x64_f8f6f4(
        av, bv0, accA, 0, 0, 0, UNITY_SCALE, 0, UNITY_SCALE);
    accB = __builtin_amdgcn_mfma_scale_f32_32x32x64_f8f6f4(
        av, bv1, accB, 0, 0, 0, UNITY_SCALE, 0, UNITY_SCALE);
    __builtin_amdgcn_s_setprio(0);
    if (step < KSTEPS - 1) {
      // outstanding here: stages for tiles step+1, step+2 (4 loads);
      // allow newest 2 -> tile step+1 landed
      asm volatile("s_waitcnt vmcnt(2)" ::: "memory");
      __builtin_amdgcn_s_barrier();
      if (step + DEPTH < KSTEPS)
        STAGE(d, step + DEPTH);
    }
  }
#undef STAGE

  // Epilogue. 32x32 C/D: col = lane&31, row = (r&3)+8*(r>>2)+4*hi.
  // Interleaved A rows: even row = dot_e, odd = dot_wy -> reg pair (r, r+1).
  #pragma unroll
  for (int rp = 0; rp < 8; ++rp) {
    const int r = 2 * rp;
    const int lb = fA * 16 + (rp & 1) + 4 * (rp >> 1) + 2 * hi;
    float4 pp = pl[lb];
    int lab = ll[lb];
    int j0 = n0 + fB0 * 32 + (l & 31);
    int j1 = j0 + 32;
    float s = termf(accA[r], accA[r + 1], pp, (j0 >= C_SZ) || (j0 == lab))
            + termf(accB[r], accB[r + 1], pp, (j1 >= C_SZ) || (j1 == lab));
    #pragma unroll
    for (int o = 1; o < 32; o <<= 1) s += __shfl_xor(s, o, 64);
    if ((l & 31) == 0) atomicAdd(&ered[lb], s);
  }
  __syncthreads();
  if (t < 64) part[(size_t)(b0 + t) * NTILES + nt] = ered[t];
}

// ---------------- kernel 4a: per-batch row sum + log1p ----------------
__global__ __launch_bounds__(256) void k_rowsum(const float* __restrict__ part,
                                                float* __restrict__ rowsum) {
  const int b = blockIdx.x;
  float s = 0.0f;
  for (int i = threadIdx.x; i < NTILES; i += 256) s += part[(size_t)b * NTILES + i];
  #pragma unroll
  for (int o = 32; o; o >>= 1) s += __shfl_xor(s, o, 64);
  __shared__ float red[4];
  if ((threadIdx.x & 63) == 0) red[threadIdx.x >> 6] = s;
  __syncthreads();
  if (threadIdx.x == 0)
    rowsum[b] = log1pf(red[0] + red[1] + red[2] + red[3]);
}

// ---------------- kernel 4b: final mean ----------------
__global__ __launch_bounds__(512) void k_final(const float* __restrict__ rowsum,
                                               float* __restrict__ out) {
  const int b = threadIdx.x;
  float v = rowsum[b];
  __shared__ float red[512];
  red[b] = v;
  __syncthreads();
  #pragma unroll
  for (int o = 256; o; o >>= 1) {
    if (b < o) red[b] += red[b + o];
    __syncthreads();
  }
  if (b == 0) out[0] = red[0] / (float)B_SZ;
}

extern "C" void kernel_launch(void* const* d_in, const int* in_sizes, int n_in,
                              void* d_out, int out_size, void* d_ws, size_t ws_size,
                              hipStream_t stream) {
  const float* emb = (const float*)d_in[0];
  const int* labels = (const int*)d_in[1];
  const float* w = (const float*)d_in[2];

  char* ws = (char*)d_ws;
  unsigned char* w8 = (unsigned char*)ws;                  // 100000*512 B
  size_t off = (size_t)C_SZ * D_SZ;
  unsigned char* A8 = (unsigned char*)(ws + off);          // 1024*512 B
  off += (size_t)2 * B_SZ * D_SZ;
  float4* params = (float4*)(ws + off);                    // 512*16 B
  off += (size_t)B_SZ * 16;
  float* part = (float*)(ws + off);                        // 512*782*4 B
  off += (size_t)B_SZ * NTILES * 4;
  float* rowsum = (float*)(ws + off);                      // 512*4 B
  off += (size_t)B_SZ * 4;

  k_norm_w<<<dim3(C_SZ / 4), dim3(256), 0, stream>>>(w, w8);
  k_prep<<<dim3(B_SZ), dim3(64), 0, stream>>>(emb, labels, w8, A8, params);
  k_gemm<<<dim3(NBLK), dim3(512), 0, stream>>>(A8, w8, params, labels, part);
  k_rowsum<<<dim3(B_SZ), dim3(256), 0, stream>>>(part, rowsum);
  k_final<<<dim3(1), dim3(512), 0, stream>>>(rowsum, (float*)d_out);
}